// Round 2
// baseline (403.644 us; speedup 1.0000x reference)
//
#include <hip/hip_runtime.h>
#include <hip/hip_bf16.h>

#define NN 50000
#define NE 600000
#define DD 128
#define RB 64            // rows per MFMA block (4 waves x 16 rows)
#define NSHARD_DIV 6250  // NN/8 node-range per XCD shard
#define GB ((NN + RB - 1) / RB)      // 782 MFMA blocks
#define EBQ ((NE + 1023) / 1024)     // 586 edge chunks (4 edges/thread)
#define SB ((NN + 1023) / 1024)      // 49 scan blocks

typedef __bf16 bfrag __attribute__((ext_vector_type(8)));
typedef float  ffrag __attribute__((ext_vector_type(4)));
typedef unsigned uintv4 __attribute__((ext_vector_type(4)));   // native vec for nontemporal
typedef unsigned uintv2 __attribute__((ext_vector_type(2)));

union frag_cast { uintv4 u4; unsigned u[4]; bfrag b; };

__device__ __forceinline__ float bfbits2f(unsigned v) { return __uint_as_float(v << 16); }
__device__ __forceinline__ unsigned f2bfbits(float f) {
    unsigned u = __float_as_uint(f);
    return (u + 0x7FFFu + ((u >> 16) & 1u)) >> 16;   // RNE
}

__device__ __forceinline__ float ld_in(const void* p, int idx, int f32) {
    return f32 ? ((const float*)p)[idx]
               : bfbits2f(((const unsigned short*)p)[idx]);
}

__device__ __forceinline__ void ld_edge_nt(const int* adj, int e, int i64, int& s, int& d) {
    if (i64) {
        s = __builtin_nontemporal_load(&adj[4 * e]);
        d = __builtin_nontemporal_load(&adj[4 * e + 2]);
    } else {
        s = __builtin_nontemporal_load(&adj[2 * e]);
        d = __builtin_nontemporal_load(&adj[2 * e + 1]);
    }
}

// ---------------- prep: weight transpose + sniff + DEG zeroing ----------------
__global__ void k_prep(const unsigned* __restrict__ Ww, const unsigned* __restrict__ adjw,
                       const void* __restrict__ We, const void* __restrict__ Wu,
                       unsigned short* __restrict__ WeT, unsigned short* __restrict__ WuT,
                       int* __restrict__ flags, int* __restrict__ deg) {
    const int tid = threadIdx.x;
    if (blockIdx.x < DD) {
        __shared__ int scnt;
        if (tid == 0) scnt = 0;
        __syncthreads();
        int c = 0;
        for (int i = tid; i < 512; i += 256) {
            unsigned e = (Ww[i] >> 7) & 0xFFu;
            c += (e >= 0x60u && e <= 0x85u) ? 1 : 0;   // plausible low-half bf16?
        }
        atomicAdd(&scnt, c);
        __syncthreads();
        const int f32 = (scnt >= 256) ? 0 : 1;
        const int k = blockIdx.x;
        if (tid < DD) {
            WeT[tid * DD + k] = (unsigned short)f2bfbits(ld_in(We, k * DD + tid, f32));
        } else {
            int n = tid - DD;
            WuT[n * DD + k] = (unsigned short)f2bfbits(ld_in(Wu, k * DD + n, f32));
        }
        return;
    }
    for (int i = (blockIdx.x - DD) * 256 + tid; i < NN; i += 64 * 256) deg[i] = 0;
    if (blockIdx.x != DD) return;
    __shared__ int cnt[2];
    if (tid < 2) cnt[tid] = 0;
    __syncthreads();
    int c0 = 0, c1 = 0;
    for (int i = tid; i < 512; i += 256) {
        unsigned e = (Ww[i] >> 7) & 0xFFu;
        c0 += (e >= 0x60u && e <= 0x85u) ? 1 : 0;
        c1 += (adjw[2 * i + 1] == 0u) ? 1 : 0;          // int64 zero high words?
    }
    atomicAdd(&cnt[0], c0);
    atomicAdd(&cnt[1], c1);
    __syncthreads();
    if (tid == 0) {
        flags[0] = (cnt[0] >= 256) ? 0 : 1;   // fp32 inputs?
        flags[1] = (cnt[1] >= 256) ? 1 : 0;   // int64 adjacency?
    }
}

// ---------------- MFMA core: A-fragments from registers, B from LDS ----------------
__device__ __forceinline__ void mfma_rows(const bfrag af[4], const unsigned short* sWT,
                                          int m, int quad, ffrag acc[8]) {
#pragma unroll
    for (int ks = 0; ks < 4; ks++) {
        const int k0 = ks * 32 + quad * 8;
#pragma unroll
        for (int ct = 0; ct < 8; ct++) {
            bfrag bf_ = *(const bfrag*)&sWT[(ct * 16 + m) * DD + k0];
            acc[ct] = __builtin_amdgcn_mfma_f32_16x16x32_bf16(af[ks], bf_, acc[ct], 0, 0, 0);
        }
    }
}

// ---------------- fused: emb GEMM (blocks < GB) || degree+slot atomics (rest) ------
__launch_bounds__(256, 5)
__global__ void k_main1(const void* __restrict__ Xp, const unsigned short* __restrict__ WTg,
                        const void* __restrict__ Bp, unsigned short* __restrict__ Hout,
                        const int* __restrict__ flags, const int* __restrict__ adj,
                        int* __restrict__ deg, uintv2* __restrict__ edg) {
    __shared__ __align__(16) unsigned short sWT[DD * DD];  // 32 KB
    const int tid = threadIdx.x;
    if (blockIdx.x >= GB) {
        // -------- edge path: degree count with returning atomics --------
        const int bb = blockIdx.x - GB;
        const int i64 = flags[1];
#pragma unroll
        for (int k = 0; k < 4; k++) {
            const int e = bb * 1024 + k * 256 + tid;
            if (e < NE) {
                int s, d;
                ld_edge_nt(adj, e, i64, s, d);
                uintv2 out;
                if ((unsigned)s < NN && (unsigned)d < NN) {
                    int ks = atomicAdd(&deg[s], 1);
                    int kd = atomicAdd(&deg[d], 1);
                    out[0] = (unsigned)s | ((unsigned)d << 16);
                    out[1] = (unsigned)ks | ((unsigned)kd << 16);  // max deg ~60 << 65536
                } else {
                    out[0] = 0xFFFFFFFFu;  // sentinel: skip in fill
                    out[1] = 0;
                }
                __builtin_nontemporal_store(out, &edg[e]);
            }
        }
        return;
    }
    // -------- emb path: h0 = relu(X @ W_emb + b) -> bf16 HA --------
    const int wave = tid >> 6;
    const int lane = tid & 63;
    const int f32  = flags[0];
    const int m    = lane & 15;
    const int quad = lane >> 4;
    const int rowbase = blockIdx.x * RB + wave * 16;
    const int row  = rowbase + m;
    const int rc   = (row < NN) ? row : (NN - 1);   // clamp for load; stores guarded

    for (int i = tid; i < 2048; i += 256)
        ((uintv4*)sWT)[i] = ((const uintv4*)WTg)[i];

    bfrag af[4];
    if (f32) {
        const float4* Xf = (const float4*)Xp;
#pragma unroll
        for (int ks = 0; ks < 4; ks++) {
            const int k0 = ks * 32 + quad * 8;
            float4 a0 = Xf[rc * 32 + (k0 >> 2)];
            float4 a1 = Xf[rc * 32 + (k0 >> 2) + 1];
            frag_cast fc;
            fc.u[0] = f2bfbits(a0.x) | (f2bfbits(a0.y) << 16);
            fc.u[1] = f2bfbits(a0.z) | (f2bfbits(a0.w) << 16);
            fc.u[2] = f2bfbits(a1.x) | (f2bfbits(a1.y) << 16);
            fc.u[3] = f2bfbits(a1.z) | (f2bfbits(a1.w) << 16);
            af[ks] = fc.b;
        }
    } else {
        const uintv4* Xv = (const uintv4*)Xp;
#pragma unroll
        for (int ks = 0; ks < 4; ks++) {
            const int k0 = ks * 32 + quad * 8;
            frag_cast fc;
            fc.u4 = Xv[rc * 16 + (k0 >> 3)];
            af[ks] = fc.b;
        }
    }
    __syncthreads();

    ffrag acc[8];
#pragma unroll
    for (int i = 0; i < 8; i++) acc[i] = (ffrag)(0.0f);
    mfma_rows(af, sWT, m, quad, acc);

#pragma unroll
    for (int ct = 0; ct < 8; ct++) {
        int col = ct * 16 + m;
        float bb = ld_in(Bp, col, f32);
#pragma unroll
        for (int reg = 0; reg < 4; reg++) {
            int orow = rowbase + quad * 4 + reg;
            if (orow < NN) {
                float z = fmaxf(acc[ct][reg] + bb, 0.0f);
                Hout[orow * DD + col] = (unsigned short)f2bfbits(z);
            }
        }
    }
}

// ---------------- hierarchical scan (wave-shuffle, 2 barriers) ----------------
__global__ void k_scan1(const int* __restrict__ deg, int* __restrict__ rows,
                        int* __restrict__ sums) {
    __shared__ int wsum[16];
    __shared__ int woff[16];
    const int tid  = threadIdx.x;
    const int wid  = tid >> 6;
    const int lane = tid & 63;
    const int i = blockIdx.x * 1024 + tid;
    int x = (i < NN) ? deg[i] : 0;
#pragma unroll
    for (int off = 1; off < 64; off <<= 1) {
        int y = __shfl_up(x, off, 64);
        if (lane >= off) x += y;
    }
    if (lane == 63) wsum[wid] = x;
    __syncthreads();
    if (wid == 0) {
        int s  = (lane < 16) ? wsum[lane] : 0;
        int xs = s;
#pragma unroll
        for (int off = 1; off < 16; off <<= 1) {
            int y = __shfl_up(xs, off, 64);
            if (lane >= off) xs += y;
        }
        if (lane < 16) woff[lane] = xs - s;
        if (lane == 15) sums[blockIdx.x] = xs;
    }
    __syncthreads();
    if (i < NN) rows[i + 1] = x + woff[wid];
}

__global__ void k_scan2(int* __restrict__ sums, int nb) {
    int t = threadIdx.x;                 // one wave of 64
    int v = (t < nb) ? sums[t] : 0;
    int x = v;
    for (int off = 1; off < 64; off <<= 1) {
        int y = __shfl_up(x, off, 64);
        if (t >= off) x += y;
    }
    if (t < nb) sums[t] = x - v;         // exclusive
}

__global__ void k_scan3(const int* __restrict__ sums, int* __restrict__ rows) {
    int i = blockIdx.x * 1024 + threadIdx.x;
    if (i < NN) {
        rows[i + 1] += sums[blockIdx.x];
        if (i == 0) rows[0] = 0;
    }
}

// ---------------- atomic-free XCD-sharded fill: slot = rows[s] + precomputed ks ----
__launch_bounds__(256)
__global__ void k_fill2(const uintv2* __restrict__ edg, const int* __restrict__ rows,
                        unsigned short* __restrict__ nbr) {
    const int shard = blockIdx.x & 7;
    const int bb = blockIdx.x >> 3;
#pragma unroll
    for (int k = 0; k < 4; k++) {
        const int e = bb * 1024 + k * 256 + threadIdx.x;
        if (e >= NE) continue;
        uintv2 v = __builtin_nontemporal_load(&edg[e]);
        if (v[0] == 0xFFFFFFFFu) continue;
        const int s = v[0] & 0xFFFFu, d = v[0] >> 16;
        if (s / NSHARD_DIV == shard) nbr[rows[s] + (v[1] & 0xFFFFu)] = (unsigned short)d;
        if (d / NSHARD_DIV == shard) nbr[rows[d] + (v[1] >> 16)]    = (unsigned short)s;
    }
}

// ---------------- vectorized gather core: 16 lanes = one row, 16B/lane ----------------
// One wave handles 4 rows concurrently (one per 16-lane quad); each VMEM instr
// moves 1KB covering 4 neighbor rows (vs 256B/1row before) -> 4x issue density.
__device__ __forceinline__ void acc8(float a[8], uintv4 v) {
#pragma unroll
    for (int i = 0; i < 4; i++) {
        a[2 * i]     += bfbits2f(v[i] & 0xFFFFu);
        a[2 * i + 1] += bfbits2f(v[i] >> 16);
    }
}

__device__ __forceinline__ uintv4 gather_row(const uintv4* __restrict__ Hv,
                                             const int* __restrict__ rows,
                                             const unsigned short* __restrict__ nbr,
                                             int rc, int cpart) {
    const int st = rows[rc], en = rows[rc + 1];
    uintv4 sv = Hv[rc * 16 + cpart];          // self term
    float a[8];
#pragma unroll
    for (int i = 0; i < 4; i++) {
        a[2 * i]     = bfbits2f(sv[i] & 0xFFFFu);
        a[2 * i + 1] = bfbits2f(sv[i] >> 16);
    }
    int j = st;
    for (; j + 4 <= en; j += 4) {             // quad-divergent trip counts: exec-masked
        int n0 = nbr[j], n1 = nbr[j + 1], n2 = nbr[j + 2], n3 = nbr[j + 3];
        uintv4 v0 = Hv[n0 * 16 + cpart];
        uintv4 v1 = Hv[n1 * 16 + cpart];
        uintv4 v2 = Hv[n2 * 16 + cpart];
        uintv4 v3 = Hv[n3 * 16 + cpart];
        acc8(a, v0); acc8(a, v1); acc8(a, v2); acc8(a, v3);
    }
    for (; j < en; ++j) acc8(a, Hv[(int)nbr[j] * 16 + cpart]);
    const float inv = 1.0f / (float)(en - st + 1);
    uintv4 pk;
#pragma unroll
    for (int i = 0; i < 4; i++)
        pk[i] = f2bfbits(a[2 * i] * inv) | (f2bfbits(a[2 * i + 1] * inv) << 16);
    return pk;
}

// ---------------- fused iteration (non-last): gather -> LDS (swizzled) -> MFMA ------
// Removes the XB round-trip and hides the GEMM under other blocks' gathers.
__launch_bounds__(256, 3)
__global__ void k_iter(const unsigned short* __restrict__ Hin, const int* __restrict__ rows,
                       const unsigned short* __restrict__ nbr,
                       const unsigned short* __restrict__ WTg, const void* __restrict__ Bp,
                       unsigned short* __restrict__ Hout, const int* __restrict__ flags) {
    __shared__ __align__(16) unsigned short sWT[DD * DD];     // 32 KB
    __shared__ __align__(16) unsigned short sXB[4 * 16 * DD]; // 16 KB, XOR-swizzled rows
    const int tid  = threadIdx.x;
    const int wave = tid >> 6;
    const int lane = tid & 63;
    const int m    = lane & 15;
    const int quad = lane >> 4;
    const int cpart = lane & 15;
    const int rowbase = blockIdx.x * RB + wave * 16;

    for (int i = tid; i < 2048; i += 256)                     // in flight during gather
        ((uintv4*)sWT)[i] = ((const uintv4*)WTg)[i];

    const uintv4* Hv = (const uintv4*)Hin;
    for (int b = 0; b < 4; b++) {
        const int r  = rowbase + b * 4 + quad;
        const int rc = (r < NN) ? r : (NN - 1);
        uintv4 pk = gather_row(Hv, rows, nbr, rc, cpart);
        const int rr = b * 4 + quad;
        unsigned off = (unsigned)(wave * 4096 + rr * 256 + cpart * 16);
        off ^= (unsigned)((rr & 7) << 4);                     // bank-balance A-frag reads
        *(uintv4*)((char*)sXB + off) = pk;
    }
    __syncthreads();

    bfrag af[4];
#pragma unroll
    for (int ks = 0; ks < 4; ks++) {
        unsigned off = (unsigned)(wave * 4096 + m * 256 + ks * 64 + quad * 16);
        off ^= (unsigned)((m & 7) << 4);
        af[ks] = *(const bfrag*)((const char*)sXB + off);
    }

    ffrag acc[8];
#pragma unroll
    for (int i = 0; i < 8; i++) acc[i] = (ffrag)(0.0f);
    mfma_rows(af, sWT, m, quad, acc);

    const int f32 = flags[0];
#pragma unroll
    for (int ct = 0; ct < 8; ct++) {
        int col = ct * 16 + m;
        float bb = ld_in(Bp, col, f32);
#pragma unroll
        for (int reg = 0; reg < 4; reg++) {
            int orow = rowbase + quad * 4 + reg;
            if (orow < NN) {
                float s = 1.0f / (1.0f + __expf(-(acc[ct][reg] + bb)));
                Hout[orow * DD + col] = (unsigned short)f2bfbits(s);
            }
        }
    }
}

// ---------------- standalone vectorized gather (last iter: input must leave d_out) ---
__launch_bounds__(256)
__global__ void k_gath2(const unsigned short* __restrict__ Hin, const int* __restrict__ rows,
                        const unsigned short* __restrict__ nbr, unsigned* __restrict__ XB32) {
    const int tid  = threadIdx.x;
    const int wave = tid >> 6;
    const int lane = tid & 63;
    const int quad = lane >> 4;
    const int cpart = lane & 15;
    const int r  = blockIdx.x * 16 + wave * 4 + quad;
    const int rc = (r < NN) ? r : (NN - 1);
    uintv4 pk = gather_row((const uintv4*)Hin, rows, nbr, rc, cpart);
    if (r < NN)
        __builtin_nontemporal_store(pk, (uintv4*)XB32 + r * 16 + cpart);
}

// ---------------- GEMM 2 (last iter): h_new = sigmoid(XB @ W_upd + b) ----------------
__launch_bounds__(256, 5)
__global__ void k_gemmB(const unsigned short* __restrict__ XB,
                        const unsigned short* __restrict__ WTg, const void* __restrict__ Bp,
                        unsigned short* __restrict__ HoutBf, float* __restrict__ HoutF,
                        const int* __restrict__ flags, int last) {
    __shared__ __align__(16) unsigned short sWT[DD * DD];  // 32 KB
    const int tid  = threadIdx.x;
    const int wave = tid >> 6;
    const int lane = tid & 63;
    const int f32  = flags[0];
    const int m    = lane & 15;
    const int quad = lane >> 4;
    const int rowbase = blockIdx.x * RB + wave * 16;
    const int row  = rowbase + m;

    for (int i = tid; i < 2048; i += 256)
        ((uintv4*)sWT)[i] = ((const uintv4*)WTg)[i];

    bfrag af[4];
    const uintv4* Xv = (const uintv4*)XB;
#pragma unroll
    for (int ks = 0; ks < 4; ks++) {
        const int k0 = ks * 32 + quad * 8;
        frag_cast fc;
        fc.u4 = __builtin_nontemporal_load(&Xv[row * 16 + (k0 >> 3)]);  // single-use stream
        af[ks] = fc.b;
    }
    __syncthreads();

    ffrag acc[8];
#pragma unroll
    for (int i = 0; i < 8; i++) acc[i] = (ffrag)(0.0f);
    mfma_rows(af, sWT, m, quad, acc);

#pragma unroll
    for (int ct = 0; ct < 8; ct++) {
        int col = ct * 16 + m;
        float bb = ld_in(Bp, col, f32);
#pragma unroll
        for (int reg = 0; reg < 4; reg++) {
            int orow = rowbase + quad * 4 + reg;
            if (orow < NN) {
                float s = 1.0f / (1.0f + __expf(-(acc[ct][reg] + bb)));
                if (!last) {
                    HoutBf[orow * DD + col] = (unsigned short)f2bfbits(s);
                } else if (f32) {
                    HoutF[orow * DD + col] = s;
                } else {
                    ((unsigned short*)HoutF)[orow * DD + col] = (unsigned short)f2bfbits(s);
                }
            }
        }
    }
}

extern "C" void kernel_launch(void* const* d_in, const int* in_sizes, int n_in,
                              void* d_out, int out_size, void* d_ws, size_t ws_size,
                              hipStream_t stream) {
    const void* X  = d_in[0];
    const void* We = d_in[1];
    const void* be = d_in[2];
    const void* Wu = d_in[3];
    const void* bu = d_in[4];
    const int* adj = (const int*)d_in[5];

    // ws: FLAGS | ROWS | SUMS | NBR(2.4M) | WeT | WuT | HW(12.8M + 16K slack)
    // HW overlays EDG2(4.8M) + DEG(200K): both dead after fill2/scan1, before it0
    // writes HW. Total ~15.5 MB.
    char* p = (char*)d_ws;
    int* FLAGS = (int*)p;                       p += 256;
    int* ROWS  = (int*)p;                       p += ((NN + 1) * 4 + 252) / 256 * 256;
    int* SUMS  = (int*)p;                       p += 256;
    unsigned short* NBR = (unsigned short*)p;   p += (size_t)2 * NE * 2;
    unsigned short* WeT = (unsigned short*)p;   p += DD * DD * 2;
    unsigned short* WuT = (unsigned short*)p;   p += DD * DD * 2;
    unsigned short* HW  = (unsigned short*)p;   // 12.8 MB + slack
    uintv2* EDG2 = (uintv2*)p;                  // overlays HW[0 .. 4.8M)
    int* DEG = (int*)(p + (size_t)NE * 8);      // overlays HW[4.8M .. 5.0M)

    // h0 lives in d_out's upper half (bytes 12.8M..25.6M)
    unsigned short* HA = (unsigned short*)d_out + (size_t)NN * DD;

    k_prep<<<DD + 64, 256, 0, stream>>>((const unsigned*)We, (const unsigned*)adj,
                                        We, Wu, WeT, WuT, FLAGS, DEG);
    k_main1<<<GB + EBQ, 256, 0, stream>>>(X, WeT, be, HA, FLAGS, adj, DEG, EDG2);
    k_scan1<<<SB, 1024, 0, stream>>>(DEG, ROWS, SUMS);
    k_scan2<<<1, 64, 0, stream>>>(SUMS, SB);
    k_scan3<<<SB, 1024, 0, stream>>>(SUMS, ROWS);
    k_fill2<<<8 * EBQ, 256, 0, stream>>>(EDG2, ROWS, NBR);

    // it0: HA -> HW (HW safe: EDG2/DEG dead). it1: HW -> HA.
    k_iter<<<GB, 256, 0, stream>>>(HA, ROWS, NBR, WuT, bu, HW, FLAGS);
    k_iter<<<GB, 256, 0, stream>>>(HW, ROWS, NBR, WuT, bu, HA, FLAGS);

    // it2 split (fused would race: HA lives inside d_out): gather HA -> HW, then
    // GEMM HW -> d_out f32 (overwrites HA only after gather consumed it).
    const int G2B = (NN + 15) / 16;              // 3125 gather blocks
    k_gath2<<<G2B, 256, 0, stream>>>(HA, ROWS, NBR, (unsigned*)HW);
    k_gemmB<<<GB, 256, 0, stream>>>(HW, WuT, bu, HA, (float*)d_out, FLAGS, 1);
}

// Round 3
// 381.053 us; speedup vs baseline: 1.0593x; 1.0593x over previous
//
#include <hip/hip_runtime.h>
#include <hip/hip_bf16.h>

#define NN 50000
#define NE 600000
#define DD 128
#define RB 64            // rows per MFMA block (4 waves x 16 rows)
#define NSHARD_DIV 6250  // NN/8 node-range per XCD shard
#define GB ((NN + RB - 1) / RB)      // 782 MFMA blocks
#define EBQ ((NE + 1023) / 1024)     // 586 edge chunks (4 edges/thread)
#define SB ((NN + 1023) / 1024)      // 49 scan blocks
#define GQB (8 * ((NN + 31) / 32))   // 12504 gather blocks (8 planes x 1563)

typedef __bf16 bfrag __attribute__((ext_vector_type(8)));
typedef float  ffrag __attribute__((ext_vector_type(4)));
typedef unsigned uintv4 __attribute__((ext_vector_type(4)));   // native vec for nontemporal
typedef unsigned uintv2 __attribute__((ext_vector_type(2)));

union frag_cast { uintv4 u4; unsigned u[4]; bfrag b; };

__device__ __forceinline__ float bfbits2f(unsigned v) { return __uint_as_float(v << 16); }
__device__ __forceinline__ unsigned f2bfbits(float f) {
    unsigned u = __float_as_uint(f);
    return (u + 0x7FFFu + ((u >> 16) & 1u)) >> 16;   // RNE
}

__device__ __forceinline__ float ld_in(const void* p, int idx, int f32) {
    return f32 ? ((const float*)p)[idx]
               : bfbits2f(((const unsigned short*)p)[idx]);
}

__device__ __forceinline__ void ld_edge_nt(const int* adj, int e, int i64, int& s, int& d) {
    if (i64) {
        s = __builtin_nontemporal_load(&adj[4 * e]);
        d = __builtin_nontemporal_load(&adj[4 * e + 2]);
    } else {
        s = __builtin_nontemporal_load(&adj[2 * e]);
        d = __builtin_nontemporal_load(&adj[2 * e + 1]);
    }
}

// ---------------- prep: weight transpose + sniff + DEG zeroing ----------------
__global__ void k_prep(const unsigned* __restrict__ Ww, const unsigned* __restrict__ adjw,
                       const void* __restrict__ We, const void* __restrict__ Wu,
                       unsigned short* __restrict__ WeT, unsigned short* __restrict__ WuT,
                       int* __restrict__ flags, int* __restrict__ deg) {
    const int tid = threadIdx.x;
    if (blockIdx.x < DD) {
        __shared__ int scnt;
        if (tid == 0) scnt = 0;
        __syncthreads();
        int c = 0;
        for (int i = tid; i < 512; i += 256) {
            unsigned e = (Ww[i] >> 7) & 0xFFu;
            c += (e >= 0x60u && e <= 0x85u) ? 1 : 0;   // plausible low-half bf16?
        }
        atomicAdd(&scnt, c);
        __syncthreads();
        const int f32 = (scnt >= 256) ? 0 : 1;
        const int k = blockIdx.x;
        if (tid < DD) {
            WeT[tid * DD + k] = (unsigned short)f2bfbits(ld_in(We, k * DD + tid, f32));
        } else {
            int n = tid - DD;
            WuT[n * DD + k] = (unsigned short)f2bfbits(ld_in(Wu, k * DD + n, f32));
        }
        return;
    }
    for (int i = (blockIdx.x - DD) * 256 + tid; i < NN; i += 64 * 256) deg[i] = 0;
    if (blockIdx.x != DD) return;
    __shared__ int cnt[2];
    if (tid < 2) cnt[tid] = 0;
    __syncthreads();
    int c0 = 0, c1 = 0;
    for (int i = tid; i < 512; i += 256) {
        unsigned e = (Ww[i] >> 7) & 0xFFu;
        c0 += (e >= 0x60u && e <= 0x85u) ? 1 : 0;
        c1 += (adjw[2 * i + 1] == 0u) ? 1 : 0;          // int64 zero high words?
    }
    atomicAdd(&cnt[0], c0);
    atomicAdd(&cnt[1], c1);
    __syncthreads();
    if (tid == 0) {
        flags[0] = (cnt[0] >= 256) ? 0 : 1;   // fp32 inputs?
        flags[1] = (cnt[1] >= 256) ? 1 : 0;   // int64 adjacency?
    }
}

// ---------------- W staging: fragment-major LDS layout (conflict-free reads) -------
// sW unit ((ct*4+ks)*4+quad)*16 + m holds W^T row (ct*16+m), cols ks*32+quad*8..+8.
// A wave's (ks,ct) read is then lane-contiguous (m fast) -> zero bank conflicts
// (old row-major layout had 256B row stride -> 16-way conflict, 2.8M counter hits).
__device__ __forceinline__ void stage_w(const uintv4* __restrict__ WTg, uintv4* sW, int tid) {
#pragma unroll
    for (int k = 0; k < 8; k++) {
        int i = k * 256 + tid;
        int row = i >> 4, u = i & 15;
        int dst = (((row >> 4) * 4 + (u >> 2)) * 4 + (u & 3)) * 16 + (row & 15);
        sW[dst] = WTg[i];
    }
}

// ---------------- MFMA core: A from registers, B fragment-major from LDS ----------
__device__ __forceinline__ void mfma_rows(const bfrag af[4], const bfrag* sW,
                                          int m, int quad, ffrag acc[8]) {
#pragma unroll
    for (int ks = 0; ks < 4; ks++) {
#pragma unroll
        for (int ct = 0; ct < 8; ct++) {
            bfrag bf_ = sW[((ct * 4 + ks) * 4 + quad) * 16 + m];
            acc[ct] = __builtin_amdgcn_mfma_f32_16x16x32_bf16(af[ks], bf_, acc[ct], 0, 0, 0);
        }
    }
}

// ---------------- fused: emb GEMM (blocks < GB) || degree+slot atomics (rest) ------
// h0 written PLANE-BLOCKED: H[plane][node][16 cols], plane = col>>4. Each 1.6 MB
// plane then fits one XCD's 4 MB L2 during the column-sharded gather.
__launch_bounds__(256, 5)
__global__ void k_main1(const void* __restrict__ Xp, const unsigned short* __restrict__ WTg,
                        const void* __restrict__ Bp, unsigned short* __restrict__ Hout,
                        const int* __restrict__ flags, const int* __restrict__ adj,
                        int* __restrict__ deg, uintv2* __restrict__ edg) {
    __shared__ __align__(16) unsigned short sWT[DD * DD];  // 32 KB
    const int tid = threadIdx.x;
    if (blockIdx.x >= GB) {
        // -------- edge path: degree count with returning atomics --------
        const int bb = blockIdx.x - GB;
        const int i64 = flags[1];
#pragma unroll
        for (int k = 0; k < 4; k++) {
            const int e = bb * 1024 + k * 256 + tid;
            if (e < NE) {
                int s, d;
                ld_edge_nt(adj, e, i64, s, d);
                uintv2 out;
                if ((unsigned)s < NN && (unsigned)d < NN) {
                    int ks = atomicAdd(&deg[s], 1);
                    int kd = atomicAdd(&deg[d], 1);
                    out[0] = (unsigned)s | ((unsigned)d << 16);
                    out[1] = (unsigned)ks | ((unsigned)kd << 16);  // max deg ~60 << 65536
                } else {
                    out[0] = 0xFFFFFFFFu;  // sentinel: skip in fill
                    out[1] = 0;
                }
                __builtin_nontemporal_store(out, &edg[e]);
            }
        }
        return;
    }
    // -------- emb path: h0 = relu(X @ W_emb + b) -> bf16 planes --------
    const int wave = tid >> 6;
    const int lane = tid & 63;
    const int f32  = flags[0];
    const int m    = lane & 15;
    const int quad = lane >> 4;
    const int rowbase = blockIdx.x * RB + wave * 16;
    const int row  = rowbase + m;
    const int rc   = (row < NN) ? row : (NN - 1);   // clamp for load; stores guarded

    stage_w((const uintv4*)WTg, (uintv4*)sWT, tid);

    bfrag af[4];
    if (f32) {
        const float4* Xf = (const float4*)Xp;
#pragma unroll
        for (int ks = 0; ks < 4; ks++) {
            const int k0 = ks * 32 + quad * 8;
            float4 a0 = Xf[rc * 32 + (k0 >> 2)];
            float4 a1 = Xf[rc * 32 + (k0 >> 2) + 1];
            frag_cast fc;
            fc.u[0] = f2bfbits(a0.x) | (f2bfbits(a0.y) << 16);
            fc.u[1] = f2bfbits(a0.z) | (f2bfbits(a0.w) << 16);
            fc.u[2] = f2bfbits(a1.x) | (f2bfbits(a1.y) << 16);
            fc.u[3] = f2bfbits(a1.z) | (f2bfbits(a1.w) << 16);
            af[ks] = fc.b;
        }
    } else {
        const uintv4* Xv = (const uintv4*)Xp;
#pragma unroll
        for (int ks = 0; ks < 4; ks++) {
            const int k0 = ks * 32 + quad * 8;
            frag_cast fc;
            fc.u4 = Xv[rc * 16 + (k0 >> 3)];
            af[ks] = fc.b;
        }
    }
    __syncthreads();

    ffrag acc[8];
#pragma unroll
    for (int i = 0; i < 8; i++) acc[i] = (ffrag)(0.0f);
    mfma_rows(af, (const bfrag*)sWT, m, quad, acc);

#pragma unroll
    for (int ct = 0; ct < 8; ct++) {
        int col = ct * 16 + m;
        float bb = ld_in(Bp, col, f32);
#pragma unroll
        for (int reg = 0; reg < 4; reg++) {
            int orow = rowbase + quad * 4 + reg;
            if (orow < NN) {
                float z = fmaxf(acc[ct][reg] + bb, 0.0f);
                Hout[ct * (NN * 16) + orow * 16 + m] = (unsigned short)f2bfbits(z);
            }
        }
    }
}

// ---------------- hierarchical scan (wave-shuffle, 2 barriers) ----------------
__global__ void k_scan1(const int* __restrict__ deg, int* __restrict__ rows,
                        int* __restrict__ sums) {
    __shared__ int wsum[16];
    __shared__ int woff[16];
    const int tid  = threadIdx.x;
    const int wid  = tid >> 6;
    const int lane = tid & 63;
    const int i = blockIdx.x * 1024 + tid;
    int x = (i < NN) ? deg[i] : 0;
#pragma unroll
    for (int off = 1; off < 64; off <<= 1) {
        int y = __shfl_up(x, off, 64);
        if (lane >= off) x += y;
    }
    if (lane == 63) wsum[wid] = x;
    __syncthreads();
    if (wid == 0) {
        int s  = (lane < 16) ? wsum[lane] : 0;
        int xs = s;
#pragma unroll
        for (int off = 1; off < 16; off <<= 1) {
            int y = __shfl_up(xs, off, 64);
            if (lane >= off) xs += y;
        }
        if (lane < 16) woff[lane] = xs - s;
        if (lane == 15) sums[blockIdx.x] = xs;
    }
    __syncthreads();
    if (i < NN) rows[i + 1] = x + woff[wid];
}

__global__ void k_scan2(int* __restrict__ sums, int nb) {
    int t = threadIdx.x;                 // one wave of 64
    int v = (t < nb) ? sums[t] : 0;
    int x = v;
    for (int off = 1; off < 64; off <<= 1) {
        int y = __shfl_up(x, off, 64);
        if (t >= off) x += y;
    }
    if (t < nb) sums[t] = x - v;         // exclusive
}

__global__ void k_scan3(const int* __restrict__ sums, int* __restrict__ rows) {
    int i = blockIdx.x * 1024 + threadIdx.x;
    if (i < NN) {
        rows[i + 1] += sums[blockIdx.x];
        if (i == 0) rows[0] = 0;
    }
}

// ---------------- atomic-free XCD-sharded fill: slot = rows[s] + precomputed ks ----
__launch_bounds__(256)
__global__ void k_fill2(const uintv2* __restrict__ edg, const int* __restrict__ rows,
                        unsigned short* __restrict__ nbr) {
    const int shard = blockIdx.x & 7;
    const int bb = blockIdx.x >> 3;
#pragma unroll
    for (int k = 0; k < 4; k++) {
        const int e = bb * 1024 + k * 256 + threadIdx.x;
        if (e >= NE) continue;
        uintv2 v = __builtin_nontemporal_load(&edg[e]);
        if (v[0] == 0xFFFFFFFFu) continue;
        const int s = v[0] & 0xFFFFu, d = v[0] >> 16;
        if (s / NSHARD_DIV == shard) nbr[rows[s] + (v[1] & 0xFFFFu)] = (unsigned short)d;
        if (d / NSHARD_DIV == shard) nbr[rows[d] + (v[1] >> 16)]    = (unsigned short)s;
    }
}

// ---------------- column-sharded gather: plane (blockIdx&7) -> one XCD's L2 --------
// H input is plane-blocked [8][NN][16cols]; each XCD's working set = 1.6 MB plane
// (fits 4 MB L2), so random neighbor reads become local L2 hits after first touch.
// 8 lanes per node (2 bf16 cols each); 8 nodes per wave.
__launch_bounds__(256)
__global__ void k_gath3(const unsigned* __restrict__ Hp, const int* __restrict__ rows,
                        const unsigned short* __restrict__ nbr,
                        unsigned* __restrict__ XB32) {
    const int shard = blockIdx.x & 7;
    const int node  = (blockIdx.x >> 3) * 32 + (threadIdx.x >> 3);
    const int cs    = threadIdx.x & 7;
    const int nc    = (node < NN) ? node : (NN - 1);
    const unsigned* P = Hp + (size_t)shard * (NN * 8);
    const int st = rows[nc], en = rows[nc + 1];
    unsigned sv = P[nc * 8 + cs];                      // self term
    float ax = bfbits2f(sv & 0xFFFFu);
    float ay = bfbits2f(sv >> 16);
    int j = st;
    for (; j + 8 <= en; j += 8) {                      // deep unroll: 16 loads in flight
        int n[8];
#pragma unroll
        for (int t = 0; t < 8; t++) n[t] = nbr[j + t];
        unsigned v[8];
#pragma unroll
        for (int t = 0; t < 8; t++) v[t] = P[n[t] * 8 + cs];
#pragma unroll
        for (int t = 0; t < 8; t++) {
            ax += bfbits2f(v[t] & 0xFFFFu);
            ay += bfbits2f(v[t] >> 16);
        }
    }
    for (; j + 2 <= en; j += 2) {
        int n0 = nbr[j], n1 = nbr[j + 1];
        unsigned v0 = P[n0 * 8 + cs], v1 = P[n1 * 8 + cs];
        ax += bfbits2f(v0 & 0xFFFFu) + bfbits2f(v1 & 0xFFFFu);
        ay += bfbits2f(v0 >> 16) + bfbits2f(v1 >> 16);
    }
    for (; j < en; ++j) {
        unsigned v = P[(int)nbr[j] * 8 + cs];
        ax += bfbits2f(v & 0xFFFFu);
        ay += bfbits2f(v >> 16);
    }
    const float inv = 1.0f / (float)(en - st + 1);
    if (node < NN) {
        unsigned pk = f2bfbits(ax * inv) | (f2bfbits(ay * inv) << 16);
        __builtin_nontemporal_store(pk, &XB32[node * 64 + shard * 8 + cs]);  // keep L2 for H
    }
}

// ---------------- GEMM 2: h_new = sigmoid(XB @ W_upd + b) ----------------
// !last: write plane-blocked bf16 (feeds next gather). last: row-major to d_out.
__launch_bounds__(256, 5)
__global__ void k_gemmB(const unsigned short* __restrict__ XB,
                        const unsigned short* __restrict__ WTg, const void* __restrict__ Bp,
                        unsigned short* __restrict__ HoutBf, float* __restrict__ HoutF,
                        const int* __restrict__ flags, int last) {
    __shared__ __align__(16) unsigned short sWT[DD * DD];  // 32 KB
    const int tid  = threadIdx.x;
    const int wave = tid >> 6;
    const int lane = tid & 63;
    const int f32  = flags[0];
    const int m    = lane & 15;
    const int quad = lane >> 4;
    const int rowbase = blockIdx.x * RB + wave * 16;
    const int row  = rowbase + m;

    stage_w((const uintv4*)WTg, (uintv4*)sWT, tid);

    bfrag af[4];
    const uintv4* Xv = (const uintv4*)XB;
#pragma unroll
    for (int ks = 0; ks < 4; ks++) {
        const int k0 = ks * 32 + quad * 8;
        frag_cast fc;
        fc.u4 = __builtin_nontemporal_load(&Xv[row * 16 + (k0 >> 3)]);  // single-use stream
        af[ks] = fc.b;
    }
    __syncthreads();

    ffrag acc[8];
#pragma unroll
    for (int i = 0; i < 8; i++) acc[i] = (ffrag)(0.0f);
    mfma_rows(af, (const bfrag*)sWT, m, quad, acc);

#pragma unroll
    for (int ct = 0; ct < 8; ct++) {
        int col = ct * 16 + m;
        float bb = ld_in(Bp, col, f32);
#pragma unroll
        for (int reg = 0; reg < 4; reg++) {
            int orow = rowbase + quad * 4 + reg;
            if (orow < NN) {
                float s = 1.0f / (1.0f + __expf(-(acc[ct][reg] + bb)));
                if (!last) {
                    HoutBf[ct * (NN * 16) + orow * 16 + m] = (unsigned short)f2bfbits(s);
                } else if (f32) {
                    HoutF[orow * DD + col] = s;
                } else {
                    ((unsigned short*)HoutF)[orow * DD + col] = (unsigned short)f2bfbits(s);
                }
            }
        }
    }
}

extern "C" void kernel_launch(void* const* d_in, const int* in_sizes, int n_in,
                              void* d_out, int out_size, void* d_ws, size_t ws_size,
                              hipStream_t stream) {
    const void* X  = d_in[0];
    const void* We = d_in[1];
    const void* be = d_in[2];
    const void* Wu = d_in[3];
    const void* bu = d_in[4];
    const int* adj = (const int*)d_in[5];

    // ws: FLAGS | ROWS | SUMS | NBR(2.4M) | WeT | WuT | HW(12.8M + 16K slack)
    // HW overlays EDG2(4.8M) + DEG(200K): both dead after fill2/scan1, before it0
    // writes HW. Total ~15.5 MB.
    char* p = (char*)d_ws;
    int* FLAGS = (int*)p;                       p += 256;
    int* ROWS  = (int*)p;                       p += ((NN + 1) * 4 + 252) / 256 * 256;
    int* SUMS  = (int*)p;                       p += 256;
    unsigned short* NBR = (unsigned short*)p;   p += (size_t)2 * NE * 2;
    unsigned short* WeT = (unsigned short*)p;   p += DD * DD * 2;
    unsigned short* WuT = (unsigned short*)p;   p += DD * DD * 2;
    unsigned short* HW  = (unsigned short*)p;   // 12.8 MB + slack (gemmB over-read)
    uintv2* EDG2 = (uintv2*)p;                  // overlays HW[0 .. 4.8M)
    int* DEG = (int*)(p + (size_t)NE * 8);      // overlays HW[4.8M .. 5.0M)

    // h planes live in d_out's upper half (bytes 12.8M..25.6M); dead before the
    // final row-major f32 write (gather consumes them first, stream-ordered).
    unsigned short* HA = (unsigned short*)d_out + (size_t)NN * DD;

    k_prep<<<DD + 64, 256, 0, stream>>>((const unsigned*)We, (const unsigned*)adj,
                                        We, Wu, WeT, WuT, FLAGS, DEG);
    k_main1<<<GB + EBQ, 256, 0, stream>>>(X, WeT, be, HA, FLAGS, adj, DEG, EDG2);
    k_scan1<<<SB, 1024, 0, stream>>>(DEG, ROWS, SUMS);
    k_scan2<<<1, 64, 0, stream>>>(SUMS, SB);
    k_scan3<<<SB, 1024, 0, stream>>>(SUMS, ROWS);
    k_fill2<<<8 * EBQ, 256, 0, stream>>>(EDG2, ROWS, NBR);

    for (int it = 0; it < 3; ++it) {
        int last = (it == 2);
        k_gath3<<<GQB, 256, 0, stream>>>((const unsigned*)HA, ROWS, NBR, (unsigned*)HW);
        k_gemmB<<<GB, 256, 0, stream>>>(HW, WuT, bu, HA, (float*)d_out, FLAGS, last);
    }
}